// Round 1
// baseline (80.983 us; speedup 1.0000x reference)
//
#include <hip/hip_runtime.h>

#define NPIX 9216          // C*H*W = 1*96*96
#define NROWS (NPIX + 1)   // 9217 rows in zonotope
#define ROW4 (NPIX / 4)    // 2304 float4 per row
#define EPSV 0.1f

// ---------------------------------------------------------------------------
// Kernel 1: compute bias/err, block-wide prefix scan for stream compaction,
// build inverse map inv[slot] = pixel index, val[slot] = err value.
// Single block of 1024 threads; NPIX = 1024 * 9 exactly.
// ---------------------------------------------------------------------------
__global__ __launch_bounds__(1024) void prep_kernel(const float* __restrict__ x,
                                                    float* __restrict__ bias,
                                                    int* __restrict__ inv,
                                                    float* __restrict__ val) {
    __shared__ int psum[1024];
    const int tid = threadIdx.x;

    // init inverse map to "no pixel" for every slot (rows past K stay zero)
    for (int s = tid; s < NROWS; s += 1024) inv[s] = -1;

    const int PER = NPIX / 1024;  // 9
    const int base = tid * PER;

    float e_loc[PER];
    int   c_loc[PER];
    int   cnt = 0;
#pragma unroll
    for (int k = 0; k < PER; ++k) {
        const int   n      = base + k;
        const float xv     = x[n];
        const float r_low  = fmaxf(EPSV - xv, 0.0f) * 0.5f;
        const float r_high = fmaxf(xv - (1.0f - EPSV), 0.0f) * 0.5f;
        bias[n] = xv + r_low - r_high;
        const float e = EPSV - r_low - r_high;
        e_loc[k] = e;
        c_loc[k] = (e >= 0.0f) ? 1 : 0;
        cnt += c_loc[k];
    }

    // inclusive Hillis-Steele scan over per-thread counts
    int v = cnt;
    psum[tid] = v;
    __syncthreads();
    for (int off = 1; off < 1024; off <<= 1) {
        const int t = (tid >= off) ? psum[tid - off] : 0;
        __syncthreads();
        v += t;
        psum[tid] = v;
        __syncthreads();
    }
    int slot = v - cnt;  // exclusive prefix (0-based); slots are 1-based

#pragma unroll
    for (int k = 0; k < PER; ++k) {
        if (c_loc[k]) {
            ++slot;                 // 1-based compacted slot == output row
            inv[slot] = base + k;   // column (pixel) for this row
            val[slot] = e_loc[k];
        }
    }
}

// ---------------------------------------------------------------------------
// Kernel 2: write the full output. Mostly zeros (vectorized float4 stores);
// row 0 = bias; row s>=1 has a single nonzero at column inv[s].
// inv[row]/val[row] reads are wave-uniform (broadcast) within a row.
// ---------------------------------------------------------------------------
__global__ __launch_bounds__(256) void write_kernel(const float* __restrict__ bias,
                                                    const int* __restrict__ inv,
                                                    const float* __restrict__ val,
                                                    float4* __restrict__ out) {
    const long long total4 = (long long)NROWS * ROW4;
    long long idx = (long long)blockIdx.x * blockDim.x + threadIdx.x;
    const long long stride = (long long)gridDim.x * blockDim.x;

    for (; idx < total4; idx += stride) {
        const int row = (int)(idx / ROW4);
        const int c4  = (int)(idx - (long long)row * ROW4);
        float4 o = make_float4(0.0f, 0.0f, 0.0f, 0.0f);
        if (row == 0) {
            o = reinterpret_cast<const float4*>(bias)[c4];
        } else {
            const int p = inv[row];          // broadcast within wave
            const int c0 = c4 * 4;
            if (p >= c0 && p < c0 + 4) {
                const float e = val[row];
                (&o.x)[p - c0] = e;
            }
        }
        out[idx] = o;
    }
}

extern "C" void kernel_launch(void* const* d_in, const int* in_sizes, int n_in,
                              void* d_out, int out_size, void* d_ws, size_t ws_size,
                              hipStream_t stream) {
    const float* x = (const float*)d_in[0];
    float* out = (float*)d_out;

    // workspace layout: bias[NPIX] | val[NROWS] | inv[NROWS]
    float* bias = (float*)d_ws;
    float* val  = bias + NPIX;
    int*   inv  = (int*)(val + NROWS);

    prep_kernel<<<1, 1024, 0, stream>>>(x, bias, inv, val);

    const long long total4 = (long long)NROWS * ROW4;  // 21,235,968
    const int block = 256;
    const int grid = 2048;  // grid-stride; ~40 iters/thread
    (void)total4;
    write_kernel<<<grid, block, 0, stream>>>(bias, inv, val, (float4*)out);
}

// Round 3
// 73.059 us; speedup vs baseline: 1.1085x; 1.1085x over previous
//
#include <hip/hip_runtime.h>

#define NPIX 9216          // C*H*W = 1*96*96
#define NROWS (NPIX + 1)   // 9217 rows in zonotope
#define ROW4 (NPIX / 4)    // 2304 float4 per row
#define EPSV 0.1f

typedef float f32x4 __attribute__((ext_vector_type(4)));

// ---------------------------------------------------------------------------
// Kernel 1: stream compaction only. Computes cond = (err >= 0) per pixel,
// block-wide exclusive scan (shuffle-based, 1 barrier), writes the inverse
// map inv[slot] = pixel index (slot is 1-based; slot 0 = bias row).
// inv pre-set to -1 so rows past the compacted count stay all-zero.
// Single block of 1024 threads; NPIX = 1024 * 9 exactly.
// ---------------------------------------------------------------------------
__global__ __launch_bounds__(1024) void prep_kernel(const float* __restrict__ x,
                                                    int* __restrict__ inv) {
    __shared__ int wsum[16];
    const int tid  = threadIdx.x;
    const int lane = tid & 63;
    const int wid  = tid >> 6;

    // init inverse map to "no pixel" for every slot
    for (int s = tid; s < NROWS; s += 1024) inv[s] = -1;

    const int PER  = NPIX / 1024;  // 9
    const int base = tid * PER;

    int c_loc[PER];
    int cnt = 0;
#pragma unroll
    for (int k = 0; k < PER; ++k) {
        const float xv     = x[base + k];
        const float r_low  = fmaxf(EPSV - xv, 0.0f) * 0.5f;
        const float r_high = fmaxf(xv - (1.0f - EPSV), 0.0f) * 0.5f;
        const float e      = EPSV - r_low - r_high;
        c_loc[k] = (e >= 0.0f) ? 1 : 0;
        cnt += c_loc[k];
    }

    // inclusive shuffle scan of per-thread counts within each wave
    int v = cnt;
#pragma unroll
    for (int off = 1; off < 64; off <<= 1) {
        const int t = __shfl_up(v, off, 64);
        if (lane >= off) v += t;
    }
    if (lane == 63) wsum[wid] = v;
    __syncthreads();   // also orders the inv[]=-1 init before the scatter below

    int woff = 0;
#pragma unroll
    for (int w = 0; w < 16; ++w) woff += (w < wid) ? wsum[w] : 0;

    int slot = woff + v - cnt;  // exclusive prefix over all threads (0-based)
#pragma unroll
    for (int k = 0; k < PER; ++k) {
        if (c_loc[k]) {
            ++slot;                 // 1-based compacted slot == output row
            inv[slot] = base + k;   // pixel (column) for this row
        }
    }
}

// ---------------------------------------------------------------------------
// Kernel 2: one block per output row. Row 0 recomputes bias from x; row s>=1
// is all zeros except a single e at column inv[s] (recomputed from x[inv[s]]).
// inv[row] / x[p] are block-uniform scalar loads. Pure streaming float4
// nontemporal stores otherwise — no divisions, no per-iteration loads.
// ---------------------------------------------------------------------------
__global__ __launch_bounds__(256) void write_kernel(const float* __restrict__ x,
                                                    const int* __restrict__ inv,
                                                    f32x4* __restrict__ out) {
    const int row = blockIdx.x;
    const int tid = threadIdx.x;
    f32x4* orow = out + (long long)row * ROW4;

    if (row == 0) {
        const f32x4* x4 = reinterpret_cast<const f32x4*>(x);
#pragma unroll
        for (int it = 0; it < 9; ++it) {
            const int c4 = tid + it * 256;
            const f32x4 xv = x4[c4];
            f32x4 o;
#pragma unroll
            for (int d = 0; d < 4; ++d) {
                const float v = xv[d];
                o[d] = v + fmaxf(EPSV - v, 0.0f) * 0.5f
                         - fmaxf(v - (1.0f - EPSV), 0.0f) * 0.5f;
            }
            __builtin_nontemporal_store(o, &orow[c4]);
        }
    } else {
        const int p  = inv[row];              // uniform: scalar load
        const int pp = (p >= 0) ? p : 0;
        const float xv     = x[pp];           // uniform: scalar load
        const float r_low  = fmaxf(EPSV - xv, 0.0f) * 0.5f;
        const float r_high = fmaxf(xv - (1.0f - EPSV), 0.0f) * 0.5f;
        const float e      = EPSV - r_low - r_high;
        // if p == -1 (unused row) no equality below ever fires -> all zeros
#pragma unroll
        for (int it = 0; it < 9; ++it) {
            const int c4 = tid + it * 256;
            const int c0 = c4 * 4;
            f32x4 o;
            o.x = (p == c0)     ? e : 0.0f;
            o.y = (p == c0 + 1) ? e : 0.0f;
            o.z = (p == c0 + 2) ? e : 0.0f;
            o.w = (p == c0 + 3) ? e : 0.0f;
            __builtin_nontemporal_store(o, &orow[c4]);
        }
    }
}

extern "C" void kernel_launch(void* const* d_in, const int* in_sizes, int n_in,
                              void* d_out, int out_size, void* d_ws, size_t ws_size,
                              hipStream_t stream) {
    const float* x = (const float*)d_in[0];
    float* out = (float*)d_out;

    int* inv = (int*)d_ws;  // NROWS ints

    prep_kernel<<<1, 1024, 0, stream>>>(x, inv);
    write_kernel<<<NROWS, 256, 0, stream>>>(x, inv, (f32x4*)out);
}